// Round 10
// baseline (234.487 us; speedup 1.0000x reference)
//
#include <hip/hip_runtime.h>
#include <cstdint>
#include <cstddef>

typedef __bf16 bf16x8 __attribute__((ext_vector_type(8)));
typedef float f32x4 __attribute__((ext_vector_type(4)));
typedef float f32x2 __attribute__((ext_vector_type(2)));
typedef float f32x16 __attribute__((ext_vector_type(16)));
typedef unsigned short ushort8 __attribute__((ext_vector_type(8)));
typedef unsigned u32x2 __attribute__((ext_vector_type(2)));
typedef float f4 __attribute__((ext_vector_type(4)));

__device__ __forceinline__ unsigned short f2bf(float f) {
    __bf16 b = (__bf16)f;
    return *(unsigned short*)&b;
}
__device__ __forceinline__ unsigned pk2bf(float a, float b) {
#if __has_builtin(__builtin_amdgcn_cvt_pk_bf16_f32)
    typedef __bf16 bf16x2v __attribute__((ext_vector_type(2)));
    bf16x2v r = __builtin_amdgcn_cvt_pk_bf16_f32(a, b);
    return *(unsigned*)&r;
#else
    __bf16 x = (__bf16)a, y = (__bf16)b;
    unsigned short ux = *(unsigned short*)&x, uy = *(unsigned short*)&y;
    return (unsigned)ux | ((unsigned)uy << 16);
#endif
}
__device__ __forceinline__ float bf2f(unsigned short u) {
    union { unsigned u; float f; } v; v.u = ((unsigned)u) << 16; return v.f;
}

#if __has_builtin(__builtin_amdgcn_exp2f)
#define EXP2(x) __builtin_amdgcn_exp2f(x)
#else
#define EXP2(x) exp2f(x)
#endif

#define GLL(g, l) __builtin_amdgcn_global_load_lds( \
    (__attribute__((address_space(1))) void*)(g), \
    (__attribute__((address_space(3))) void*)(l), 16, 0, 0)

#define CS 0.18033688011112042f   /* 0.125 * log2(e) */

// ---------------------------------------------------------------------------
// 1. prep: grid-partitioned. Blocks 0..4095: convert the four 512x512 fp32
//    weight matrices to bf16. Blocks 4096..4351: GroupNorm partial stats.
// ---------------------------------------------------------------------------
__global__ __launch_bounds__(256) void prep(
    const float* __restrict__ wq, const float* __restrict__ wk,
    const float* __restrict__ wv, const float* __restrict__ wo,
    unsigned short* __restrict__ wb,
    const float* __restrict__ x, float* __restrict__ part)
{
    const int bid = blockIdx.x;
    if (bid < 4096) {
        int i = bid * 256 + threadIdx.x;
        const float* src = (i < 262144) ? wq : (i < 524288) ? wk : (i < 786432) ? wv : wo;
        wb[i] = f2bf(src[i & 262143]);
        return;
    }
    const int idx = bid - 4096;           // 256 = 64 bg x 4 quarters
    const int q = idx & 3, bg = idx >> 2;
    const f4* xv = (const f4*)(x + (size_t)bg * 65536 + q * 16384);
    float s = 0.f, sq = 0.f;
    for (int i = threadIdx.x; i < 4096; i += 256) {
        f4 v = xv[i];
        s  += v.x + v.y + v.z + v.w;
        sq += v.x * v.x + v.y * v.y + v.z * v.z + v.w * v.w;
    }
    #pragma unroll
    for (int off = 32; off > 0; off >>= 1) {
        s  += __shfl_xor(s, off, 64);
        sq += __shfl_xor(sq, off, 64);
    }
    __shared__ float red[8];
    const int w = threadIdx.x >> 6, lane = threadIdx.x & 63;
    if (lane == 0) { red[w] = s; red[4 + w] = sq; }
    __syncthreads();
    if (threadIdx.x == 0) {
        part[(bg * 4 + q) * 2]     = red[0] + red[1] + red[2] + red[3];
        part[(bg * 4 + q) * 2 + 1] = red[4] + red[5] + red[6] + red[7];
    }
}

// ---------------------------------------------------------------------------
// 2. GroupNorm apply -> h bf16 in [B*N, C] layout.
// ---------------------------------------------------------------------------
__global__ __launch_bounds__(256) void gn_apply(
    const float* __restrict__ x, const float* __restrict__ gamma,
    const float* __restrict__ beta, const float* __restrict__ part,
    unsigned short* __restrict__ h)
{
    const int q = blockIdx.x, bg = blockIdx.y;
    const int b = bg >> 5, g = bg & 31;
    float s = 0.f, sq = 0.f;
    #pragma unroll
    for (int j = 0; j < 4; ++j) {
        s  += part[(bg * 4 + j) * 2];
        sq += part[(bg * 4 + j) * 2 + 1];
    }
    const float mean = s * (1.f / 65536.f);
    const float rstd = rsqrtf(sq * (1.f / 65536.f) - mean * mean + 1e-5f);

    float gm[16], bt[16];
    #pragma unroll
    for (int c = 0; c < 16; ++c) {
        gm[c] = gamma[g * 16 + c] * rstd;
        bt[c] = beta[g * 16 + c];
    }
    const float* xg = x + (size_t)bg * 65536;
    const int n0 = q * 1024 + threadIdx.x * 4;
    float val[16][4];
    #pragma unroll
    for (int c = 0; c < 16; ++c) {
        f4 v = *(const f4*)&xg[(size_t)c * 4096 + n0];
        val[c][0] = (v.x - mean) * gm[c] + bt[c];
        val[c][1] = (v.y - mean) * gm[c] + bt[c];
        val[c][2] = (v.z - mean) * gm[c] + bt[c];
        val[c][3] = (v.w - mean) * gm[c] + bt[c];
    }
    #pragma unroll
    for (int nn = 0; nn < 4; ++nn) {
        ushort8 v0, v1;
        #pragma unroll
        for (int c = 0; c < 8; ++c)  v0[c]     = f2bf(val[c][nn]);
        #pragma unroll
        for (int c = 8; c < 16; ++c) v1[c - 8] = f2bf(val[c][nn]);
        unsigned short* dst = h + ((size_t)(b * 4096 + n0 + nn)) * 512 + g * 16;
        *(ushort8*)dst = v0;
        *(ushort8*)(dst + 8) = v1;
    }
}

// ---------------------------------------------------------------------------
// 3. bf16 GEMM  C[i,j] = sum_k A[i,k]*Bt[j,k] (+bias, +epilogue)
//    MODE 0 (BM=128): fused QKV. Q cols -> qout (pre-scaled CS), K -> kout,
//                     V -> vt[bh][d][n] (fused transpose). GLL staging.
//    MODE 1 (BM=64):  Bt = opart (2 key-split partials); B-staging fuses
//                     combine: (o0+o1)/(l0+l1) -> bf16 into LDS. Out fp32
//                     transposed to [B,C,H,W] + residual, bias by i.
// ---------------------------------------------------------------------------
template <int MODE, int BM>
__global__ __launch_bounds__(256, 2) void gemm_bt(
    const unsigned short* __restrict__ A,   // [M,K] bf16
    const unsigned short* __restrict__ Bt,  // MODE0: [N,K] bf16 / MODE1: opart
    const float* __restrict__ bias0,
    const float* __restrict__ bias1,
    const float* __restrict__ bias2,
    const float* __restrict__ resid,
    void* __restrict__ outp,                // MODE0: qout / MODE1: fp32 out
    unsigned short* __restrict__ kout,
    unsigned short* __restrict__ vtout,
    const float* __restrict__ lbufp,        // MODE1 only
    int M, int N, int K)
{
    constexpr int MT = BM / 32;             // m-frags per wave
    __shared__ __attribute__((aligned(16))) unsigned short As[BM * 32];
    __shared__ __attribute__((aligned(16))) unsigned short Bs[128 * 32];
    const int t = threadIdx.x;
    const int w = t >> 6, lane = t & 63;
    const int l15 = lane & 15, l4 = lane >> 4;
    const int bm = blockIdx.y, bn = blockIdx.x;
    const int wm = (w >> 1) * (BM / 2), wn = (w & 1) * 64;

    f32x4 acc[MT][4] = {};

    const int srow = t >> 2;
    const int sc8  = (t & 3) * 8;

    const unsigned short* gA0 = A + (size_t)(bm * BM + srow) * K + sc8;
    unsigned short* lA0 = &As[w * 512];

    // MODE0 B staging pointers
    const unsigned short* gB0 = Bt + (size_t)(bn * 128 + srow) * K + sc8;
    const unsigned short* gB1 = gB0 + (size_t)64 * K;
    unsigned short* lB0 = &Bs[w * 512];
    unsigned short* lB1 = &Bs[2048 + w * 512];

    // MODE1 combine-staging row decomposition (B rows are m = b*4096+q)
    const int r0 = bn * 128 + srow, r1 = r0 + 64;
    const int b0r = r0 >> 12, q0r = r0 & 4095;
    const int b1r = r1 >> 12, q1r = r1 & 4095;

    for (int k0 = 0; k0 < K; k0 += 32) {
        __syncthreads();
        GLL(gA0 + k0, lA0);
        if (BM == 128) GLL(gA0 + (size_t)64 * K + k0, &As[2048 + w * 512]);
        if (MODE == 0) {
            GLL(gB0 + k0, lB0);
            GLL(gB1 + k0, lB1);
        } else {
            const int c = k0 + sc8;
            const int hh = c >> 6, dd = c & 63;
            const size_t row0 = ((size_t)(b0r * 8 + hh) << 12) + q0r;
            const size_t row1 = ((size_t)(b1r * 8 + hh) << 12) + q1r;
            ushort8 p00 = *(const ushort8*)(Bt + row0 * 64 + dd);
            ushort8 p01 = *(const ushort8*)(Bt + (row0 + 65536) * 64 + dd);
            ushort8 p10 = *(const ushort8*)(Bt + row1 * 64 + dd);
            ushort8 p11 = *(const ushort8*)(Bt + (row1 + 65536) * 64 + dd);
            float inv0 = 1.f / (lbufp[row0] + lbufp[row0 + 65536]);
            float inv1 = 1.f / (lbufp[row1] + lbufp[row1 + 65536]);
            ushort8 c0, c1;
            #pragma unroll
            for (int i = 0; i < 8; ++i) {
                c0[i] = f2bf((bf2f(p00[i]) + bf2f(p01[i])) * inv0);
                c1[i] = f2bf((bf2f(p10[i]) + bf2f(p11[i])) * inv1);
            }
            *(ushort8*)&Bs[t * 8] = c0;
            *(ushort8*)&Bs[2048 + t * 8] = c1;
        }
        __syncthreads();

        bf16x8 af[MT], bfr[4];
        #pragma unroll
        for (int mt = 0; mt < MT; ++mt)
            af[mt] = *(const bf16x8*)&As[(wm + mt * 16 + l15) * 32 + l4 * 8];
        #pragma unroll
        for (int nt = 0; nt < 4; ++nt)
            bfr[nt] = *(const bf16x8*)&Bs[(wn + nt * 16 + l15) * 32 + l4 * 8];
        #pragma unroll
        for (int mt = 0; mt < MT; ++mt)
            #pragma unroll
            for (int nt = 0; nt < 4; ++nt)
                acc[mt][nt] = __builtin_amdgcn_mfma_f32_16x16x32_bf16(
                    af[mt], bfr[nt], acc[mt][nt], 0, 0, 0);
    }

    if (MODE == 0) {
        unsigned short* qout = (unsigned short*)outp;
        #pragma unroll
        for (int nt = 0; nt < 4; ++nt) {
            int col = bn * 128 + wn + nt * 16 + l15;
            const float* bp = (col < 512) ? bias0 : (col < 1024) ? bias1 : bias2;
            float bv = bp[col & 511];
            if (col < 1024) {                   // Q (pre-scaled) / K compact
                unsigned short* dst = (col < 512) ? qout : kout;
                int cc = col & 511;
                float sc = (col < 512) ? CS : 1.0f;
                #pragma unroll
                for (int mt = 0; mt < MT; ++mt)
                    #pragma unroll
                    for (int r = 0; r < 4; ++r) {
                        int row = bm * BM + wm + mt * 16 + l4 * 4 + r;
                        dst[(size_t)row * 512 + cc] = f2bf((acc[mt][nt][r] + bv) * sc);
                    }
            } else {                            // V -> vt[bh][d][n] directly
                int hd = col - 1024;            // h*64 + d
                #pragma unroll
                for (int mt = 0; mt < MT; ++mt) {
                    int m = bm * BM + wm + mt * 16 + l4 * 4;   // n base (r=0)
                    int bb = m >> 12, n = m & 4095;
                    unsigned u0 = pk2bf(acc[mt][nt][0] + bv, acc[mt][nt][1] + bv);
                    unsigned u1 = pk2bf(acc[mt][nt][2] + bv, acc[mt][nt][3] + bv);
                    unsigned short* dst = vtout +
                        ((size_t)(bb * 8 + (hd >> 6)) * 64 + (hd & 63)) * 4096 + n;
                    *(u32x2*)dst = (u32x2){u0, u1};
                }
            }
        }
    } else {
        float* outF = (float*)outp;
        #pragma unroll
        for (int mt = 0; mt < MT; ++mt)
            #pragma unroll
            for (int nt = 0; nt < 4; ++nt)
                #pragma unroll
                for (int r = 0; r < 4; ++r) {
                    int c = bm * BM + wm + mt * 16 + l4 * 4 + r;
                    int m = bn * 128 + wn + nt * 16 + l15;
                    int b = m >> 12, n = m & 4095;
                    size_t idx = ((size_t)(b * 512 + c)) * 4096 + n;
                    outF[idx] = acc[mt][nt][r] + bias0[c] + resid[idx];
                }
    }
}

// ---------------------------------------------------------------------------
// 4. Flash attention, 32x32x16 MFMA, 64 q/wave, fixed-shift softmax,
//    2-way key split. Block = 4 waves x 64 q = 256 q of one (b,h), 2048 keys.
//    Monolithic phases; KEY-PERMUTED K staging (pi = [0-3, 8-11, 4-7, 12-15]
//    per 16-block) so S^T C-layout register order == PV B-operand key order
//    (sequential pack, no cross-lane ops). launch_bounds(256,2) — 3 waves
//    spills (R6/R7). Epilogue: COALESCED via LDS transpose (direct dword
//    scatter cost ~7 us in R6-R9). Emits UNNORMALIZED bf16 O-partials + fp32
//    l-partials; the final GEMM's B-staging does the combine.
// ---------------------------------------------------------------------------
__global__ __launch_bounds__(256, 2) void attn_kernel(
    const unsigned short* __restrict__ qb, const unsigned short* __restrict__ kb,
    const unsigned short* __restrict__ vt,
    unsigned short* __restrict__ opart, float* __restrict__ lbuf)
{
    // 36 KB shared: K/V staging during the loop, Oepi transpose in epilogue
    __shared__ __attribute__((aligned(16))) unsigned short smem[256 * 72];
    unsigned short (*Ks)[72]  = (unsigned short(*)[72])smem;
    unsigned short (*Vts)[72] = (unsigned short(*)[72])(smem + 64 * 72);
    unsigned short (*Oepi)[72] = (unsigned short(*)[72])smem;

    const int bh = blockIdx.y, b = bh >> 3, h = bh & 7;
    const int qbase = blockIdx.x * 256;
    const int s = blockIdx.z, ks0 = s * 2048;
    const int t = threadIdx.x, w = t >> 6, lane = t & 63;
    const int l31 = lane & 31, h5 = lane >> 5;

    const unsigned short* Qg = qb + ((size_t)(b * 4096 + qbase + w * 64)) * 512 + h * 64;
    const unsigned short* Kg = kb + ((size_t)(b * 4096 + ks0)) * 512 + h * 64;
    const unsigned short* Vg = vt + ((size_t)bh) * 64 * 4096 + ks0;

    // Q fragments (B-operand, persistent): q=qt*32+l31, d=kc*16+h5*8+j
    bf16x8 qf[2][4];
    #pragma unroll
    for (int qt = 0; qt < 2; ++qt)
        #pragma unroll
        for (int kc = 0; kc < 4; ++kc)
            qf[qt][kc] = *(const bf16x8*)(Qg + (size_t)(qt * 32 + l31) * 512 + kc * 16 + h5 * 8);

    f32x16 Oacc[2][2] = {};      // [dt][qt], C-layout: col=q, row=d
    float li[2] = {0.f, 0.f};

    // staging: 256 threads x 32 B for each of K (8 KB) and V^T (8 KB)
    // K slot sr holds logical key pi(sr): pi swaps 4-groups 1<->2 per 16-block
    const int sr = t >> 2, sc = (t & 3) * 16;
    const int grp = (sr >> 2) & 3;
    const int srcrow = (grp == 1) ? sr + 4 : (grp == 2) ? sr - 4 : sr;
    const unsigned short* gK = Kg + (size_t)srcrow * 512 + sc;
    const unsigned short* gV = Vg + (size_t)sr * 4096 + sc;
    unsigned short* lK = &Ks[sr][sc];
    unsigned short* lV = &Vts[sr][sc];

    ushort8 kr[2], vr[2];
    kr[0] = *(const ushort8*)(gK);
    kr[1] = *(const ushort8*)(gK + 8);
    vr[0] = *(const ushort8*)(gV);
    vr[1] = *(const ushort8*)(gV + 8);

    for (int kt = 0; kt < 32; ++kt) {
        __syncthreads();
        *(ushort8*)(lK)     = kr[0];
        *(ushort8*)(lK + 8) = kr[1];
        *(ushort8*)(lV)     = vr[0];
        *(ushort8*)(lV + 8) = vr[1];
        __syncthreads();
        if (kt < 31) {   // prefetch next tile into registers
            const unsigned short* nk = gK + (size_t)(kt + 1) * 64 * 512;
            const unsigned short* nv = gV + (kt + 1) * 64;
            kr[0] = *(const ushort8*)(nk);
            kr[1] = *(const ushort8*)(nk + 8);
            vr[0] = *(const ushort8*)(nv);
            vr[1] = *(const ushort8*)(nv + 8);
        }

        // ---- S phase: 16-MFMA burst, St[qt][ct] (scale pre-folded in Q) ----
        f32x16 St[2][2] = {};
        #pragma unroll
        for (int ct = 0; ct < 2; ++ct)
            #pragma unroll
            for (int kc = 0; kc < 4; ++kc) {
                bf16x8 kf = *(const bf16x8*)&Ks[ct * 32 + l31][kc * 16 + h5 * 8];
                St[0][ct] = __builtin_amdgcn_mfma_f32_32x32x16_bf16(kf, qf[0][kc], St[0][ct], 0, 0, 0);
                St[1][ct] = __builtin_amdgcn_mfma_f32_32x32x16_bf16(kf, qf[1][kc], St[1][ct], 0, 0, 0);
            }

        // ---- softmax phase: exp2, paired sums, sequential pack (pi order) --
        union PU { unsigned u[4]; bf16x8 v; };
        PU pf[2][4];
        #pragma unroll
        for (int qt = 0; qt < 2; ++qt) {
            f32x2 a2 = {0.f, 0.f};
            #pragma unroll
            for (int ct = 0; ct < 2; ++ct) {
                #pragma unroll
                for (int r = 0; r < 16; ++r)
                    St[qt][ct][r] = EXP2(St[qt][ct][r]);
                #pragma unroll
                for (int r = 0; r < 8; ++r) {
                    f32x2 p = {St[qt][ct][2 * r], St[qt][ct][2 * r + 1]};
                    a2 += p;
                }
                #pragma unroll
                for (int kkl = 0; kkl < 2; ++kkl)
                    #pragma unroll
                    for (int i = 0; i < 4; ++i)
                        pf[qt][ct * 2 + kkl].u[i] =
                            pk2bf(St[qt][ct][kkl * 8 + 2 * i], St[qt][ct][kkl * 8 + 2 * i + 1]);
            }
            li[qt] += a2[0] + a2[1];
        }

        // ---- PV phase: 16-MFMA burst ----
        #pragma unroll
        for (int kkl = 0; kkl < 4; ++kkl)
            #pragma unroll
            for (int dt = 0; dt < 2; ++dt) {
                bf16x8 vf = *(const bf16x8*)&Vts[dt * 32 + l31][kkl * 16 + h5 * 8];
                Oacc[dt][0] = __builtin_amdgcn_mfma_f32_32x32x16_bf16(vf, pf[0][kkl].v, Oacc[dt][0], 0, 0, 0);
                Oacc[dt][1] = __builtin_amdgcn_mfma_f32_32x32x16_bf16(vf, pf[1][kkl].v, Oacc[dt][1], 0, 0, 0);
            }
    }

    // ---- epilogue: UNNORMALIZED partials via LDS transpose (coalesced) ----
    __syncthreads();     // all waves done reading Ks/Vts before overwrite
    #pragma unroll
    for (int qt = 0; qt < 2; ++qt) {
        float lf = li[qt] + __shfl_xor(li[qt], 32, 64);
        size_t qrow = ((size_t)s * 16 + bh) * 4096 + qbase + w * 64 + qt * 32 + l31;
        if (h5 == 0) lbuf[qrow] = lf;
        #pragma unroll
        for (int dt = 0; dt < 2; ++dt)
            #pragma unroll
            for (int p = 0; p < 8; ++p) {
                int d = dt * 32 + 2 * (p & 1) + 8 * (p >> 1) + 4 * h5;
                unsigned u = pk2bf(Oacc[dt][qt][2 * p], Oacc[dt][qt][2 * p + 1]);
                *(unsigned*)&Oepi[w * 64 + qt * 32 + l31][d] = u;
            }
    }
    // same-wave read-back: 16B coalesced-combinable stores of [q][64] rows
    unsigned short* Og = opart +
        (((size_t)s * 16 + bh) * 4096 + qbase + w * 64) * 64;
    #pragma unroll
    for (int c8 = 0; c8 < 8; ++c8) {
        ushort8 val = *(const ushort8*)&Oepi[w * 64 + lane][c8 * 8];
        *(ushort8*)(Og + (size_t)lane * 64 + c8 * 8) = val;
    }
}

// ---------------------------------------------------------------------------
// launch
// ---------------------------------------------------------------------------
extern "C" void kernel_launch(void* const* d_in, const int* in_sizes, int n_in,
                              void* d_out, int out_size, void* d_ws, size_t ws_size,
                              hipStream_t stream) {
    const float* x     = (const float*)d_in[0];
    const float* gamma = (const float*)d_in[1];
    const float* beta  = (const float*)d_in[2];
    const float* Wq    = (const float*)d_in[3];
    const float* bq    = (const float*)d_in[4];
    const float* Wk    = (const float*)d_in[5];
    const float* bk    = (const float*)d_in[6];
    const float* Wv    = (const float*)d_in[7];
    const float* bv    = (const float*)d_in[8];
    const float* Wo    = (const float*)d_in[9];
    const float* bo    = (const float*)d_in[10];
    float* out = (float*)d_out;

    char* ws = (char*)d_ws;
    const size_t MB = 1024 * 1024;
    const size_t KB = 1024;
    // Skewed, non-overlapping layout (bases not congruent mod 8MB):
    unsigned short* qbuf   = (unsigned short*)(ws);                     // 8MB
    unsigned short* kbuf   = (unsigned short*)(ws + 8 * MB + 64 * KB);  // 8MB
    unsigned short* vtb    = (unsigned short*)(ws + 16 * MB + 192 * KB);// 8MB
    unsigned short* h      = (unsigned short*)(ws + 24 * MB + 320 * KB);// 8MB
    unsigned short* opart  = (unsigned short*)(ws + 33 * MB);           // 16MB
    unsigned short* wb     = (unsigned short*)(ws + 49 * MB + 64 * KB); // 2MB
    float*          gnpart = (float*)(ws + 51 * MB + 128 * KB);         // 4KB
    float*          lbuf   = (float*)(ws + 51 * MB + 192 * KB);         // 512KB

    prep<<<dim3(4352), dim3(256), 0, stream>>>(Wq, Wk, Wv, Wo, wb, x, gnpart);
    gn_apply<<<dim3(4, 64), dim3(256), 0, stream>>>(x, gamma, beta, gnpart, h);

    // fused qkv: Q->qbuf (CS-scaled), K->kbuf, V->vtb (transposed)
    gemm_bt<0, 128><<<dim3(12, 64), dim3(256), 0, stream>>>(
        h, wb, bq, bk, bv, nullptr, qbuf, kbuf, vtb, nullptr, 8192, 1536, 512);

    attn_kernel<<<dim3(16, 16, 2), dim3(256), 0, stream>>>(qbuf, kbuf, vtb, opart, lbuf);

    // out[b,c,n] = x + (O @ Wo^T + bo)^T ; B-staging combines the 2 partials
    gemm_bt<1, 64><<<dim3(64, 8), dim3(256), 0, stream>>>(
        wb + 786432, opart, bo, nullptr, nullptr, x, out, nullptr, nullptr,
        lbuf, 512, 8192, 512);
}